// Round 10
// baseline (198.684 us; speedup 1.0000x reference)
//
#include <hip/hip_runtime.h>
#include <math.h>

constexpr int B = 4;
constexpr int N = 8192;
constexpr int KNN = 8;
constexpr int NCELL = 4096;              // 16^3 Morton cells
constexpr int GSIZE = 16;                // points per group
constexpr int NGRP = N / GSIZE;          // 512 groups per cloud-batch
constexpr int NCB = 2 * B;               // cloud-batches (0-3 pred, 4-7 tgt)

// Insert tv into sorted ascending d[0..7]. Exact: d'[0]=min(d0,tv),
// d'[i]=med3(d[i-1],d[i],tv). 8 independent ops. INF insert is a no-op.
__device__ __forceinline__ void insert8(float (&d)[KNN], float tv) {
  float n0 = fminf(d[0], tv);
  float n1 = __builtin_amdgcn_fmed3f(d[0], d[1], tv);
  float n2 = __builtin_amdgcn_fmed3f(d[1], d[2], tv);
  float n3 = __builtin_amdgcn_fmed3f(d[2], d[3], tv);
  float n4 = __builtin_amdgcn_fmed3f(d[3], d[4], tv);
  float n5 = __builtin_amdgcn_fmed3f(d[4], d[5], tv);
  float n6 = __builtin_amdgcn_fmed3f(d[5], d[6], tv);
  float n7 = __builtin_amdgcn_fmed3f(d[6], d[7], tv);
  d[0] = n0; d[1] = n1; d[2] = n2; d[3] = n3;
  d[4] = n4; d[5] = n5; d[6] = n6; d[7] = n7;
}

__device__ __forceinline__ int morton3(int x, int y, int z) {
  int m = 0;
#pragma unroll
  for (int b = 0; b < 4; ++b)
    m |= (((x >> b) & 1) << (3 * b + 2)) | (((y >> b) & 1) << (3 * b + 1)) |
         (((z >> b) & 1) << (3 * b + 0));
  return m;
}

__device__ __forceinline__ int point_cell(float x, float y, float z) {
  int cx = (int)fminf(fmaxf((x + 4.0f) * 2.0f, 0.0f), 15.0f);
  int cy = (int)fminf(fmaxf((y + 4.0f) * 2.0f, 0.0f), 15.0f);
  int cz = (int)fminf(fmaxf((z + 4.0f) * 2.0f, 0.0f), 15.0f);
  return morton3(cx, cy, cz);
}

// Collapse each byte of a 64-bit ballot to one bit (bit k = byte k != 0).
__device__ __forceinline__ unsigned bytes_to_bits(unsigned long long b) {
  b |= b >> 4; b &= 0x0F0F0F0F0F0F0F0Full;
  b |= b >> 2; b &= 0x0303030303030303ull;
  b |= b >> 1; b &= 0x0101010101010101ull;
  return (unsigned)((b * 0x0102040810204080ull) >> 56) & 0xFF;
}

// One block per cloud-batch (8 blocks x 1024 threads). LDS histogram ->
// in-block scan (global starts) -> scatter (points in registers) ->
// group AABBs. Verified structure (absmax 0 since round 4).
__global__ __launch_bounds__(1024) void prep_kernel(
    const float* __restrict__ src, const float* __restrict__ tgt,
    const float* __restrict__ flow, float4* __restrict__ pred_s,
    float4* __restrict__ tgt_s, int* __restrict__ starts,
    float4* __restrict__ gbox, float* __restrict__ out) {
  __shared__ int hist[NCELL];              // 16 KB: counts -> cursor
  __shared__ int wsum[16];
  int tid = threadIdx.x, cb = blockIdx.x;
  int cloud = cb >> 2, batch = cb & 3;
  if (cb == 0 && tid == 0) out[0] = 0.0f;

  for (int i = tid; i < NCELL; i += 1024) hist[i] = 0;
  __syncthreads();

  const float* __restrict__ bp = (cloud == 0 ? src : tgt) + batch * N * 3;
  const float* __restrict__ bf = flow + batch * N * 3;
  float4 pt[8];
  int cell[8];
#pragma unroll
  for (int k = 0; k < 8; ++k) {
    int i = k * 1024 + tid;
    float x = bp[3 * i + 0], y = bp[3 * i + 1], z = bp[3 * i + 2];
    if (cloud == 0) { x += bf[3 * i + 0]; y += bf[3 * i + 1]; z += bf[3 * i + 2]; }
    pt[k] = make_float4(x, y, z, 0.5f * (x * x + y * y + z * z));
    cell[k] = point_cell(x, y, z);
    atomicAdd(&hist[cell[k]], 1);
  }
  __syncthreads();

  int b4 = tid * 4;
  int h0v = hist[b4 + 0], h1v = hist[b4 + 1];
  int h2v = hist[b4 + 2], h3v = hist[b4 + 3];
  int s = h0v + h1v + h2v + h3v;
  int lane = tid & 63, w = tid >> 6;
  int incl = s;
#pragma unroll
  for (int off = 1; off < 64; off <<= 1) {
    int u = __shfl_up(incl, off, 64);
    if (lane >= off) incl += u;
  }
  if (lane == 63) wsum[w] = incl;
  __syncthreads();
  if (tid < 16) {
    int v = wsum[tid], inc = v;
#pragma unroll
    for (int off = 1; off < 16; off <<= 1) {
      int u = __shfl_up(inc, off, 64);
      if (tid >= off) inc += u;
    }
    wsum[tid] = inc - v;
  }
  __syncthreads();
  int run = incl - s + wsum[w];
  int* __restrict__ stg = starts + cb * (NCELL + 1);
  stg[b4 + 0] = run; hist[b4 + 0] = run; run += h0v;
  stg[b4 + 1] = run; hist[b4 + 1] = run; run += h1v;
  stg[b4 + 2] = run; hist[b4 + 2] = run; run += h2v;
  stg[b4 + 3] = run; hist[b4 + 3] = run; run += h3v;
  if (tid == 0) stg[NCELL] = N;
  __syncthreads();

  float4* __restrict__ dst = (cloud == 0 ? pred_s : tgt_s) + batch * N;
#pragma unroll
  for (int k = 0; k < 8; ++k) {
    int pos = atomicAdd(&hist[cell[k]], 1);
    dst[pos] = pt[k];
  }
  __threadfence_block();
  __syncthreads();

  if (tid < NGRP) {
    const float4* __restrict__ sp = dst + tid * GSIZE;
    float lx = INFINITY, ly = INFINITY, lz = INFINITY;
    float hx = -INFINITY, hy = -INFINITY, hz = -INFINITY;
#pragma unroll
    for (int t = 0; t < GSIZE; ++t) {
      float4 p = sp[t];
      lx = fminf(lx, p.x); ly = fminf(ly, p.y); lz = fminf(lz, p.z);
      hx = fmaxf(hx, p.x); hy = fmaxf(hy, p.y); hz = fmaxf(hz, p.z);
    }
    gbox[cb * 2 * NGRP + 2 * tid + 0] = make_float4(lx, ly, lz, 0.0f);
    gbox[cb * 2 * NGRP + 2 * tid + 1] = make_float4(hx, hy, hz, 0.0f);
  }
}

// Wave = 8 consecutive sorted queries (qi = lane&7) x 8 point-slots
// (slot = lane>>3). Dense: group of 16 pts in 2 rounds, all lanes active.
// Seed = rank-matched super's 8 groups; ONE slot-merge gives the exact seed
// d8 -> thr (>= final d8, fixed); slot0 keeps the merged list, slots 1-7
// reset to INF (drained points are disjoint from seeds -> no duplicates).
// Flat tests: all 512 group boxes (LDS) in 64 unrolled independent rounds;
// ballots OR 8-query verdicts into 8 compile-time-indexed u64 masks.
// Drain: per-mask 2-deep software pipeline (next group's coalesced loads in
// flight during current inserts). Skips exact: boxmin <= true dist^2,
// thr >= final d8 (1e-5 margins cover fp). Query chunks permuted within each
// cloud-batch to load-balance blocks across CUs.
__global__ __launch_bounds__(256, 8) void chamfer_kernel(
    const float4* __restrict__ pred_s, const float4* __restrict__ tgt_s,
    const int* __restrict__ starts, const float4* __restrict__ gbox,
    float* __restrict__ out) {
  __shared__ float4 gB[2 * NGRP];          // 16 KB group boxes
  __shared__ float bsum[4];
  int tid = threadIdx.x;
  int lane = tid & 63;
  int wv = tid >> 6;
  int qi = lane & 7;
  int slot = lane >> 3;
  int wgid = blockIdx.x * 4 + wv;          // 0..8191
  int cbq = wgid >> 10;                    // 1024 waves per cloud-batch
  int local = wgid & 1023;
  int perm = (local * 331) & 1023;         // bijective: balance block loads
  int ccb = cbq ^ 4;                       // opposite cloud, same batch
  const float4* __restrict__ qarr = (cbq < 4 ? pred_s : tgt_s) + (cbq & 3) * N;
  const float4* __restrict__ parr = (ccb < 4 ? pred_s : tgt_s) + (ccb & 3) * N;
  const int* __restrict__ st = starts + ccb * (NCELL + 1);
  const float4* __restrict__ gbg = gbox + ccb * (2 * NGRP);

  // Stage candidate cloud's group boxes (coalesced, once per block).
  for (int i = tid; i < 2 * NGRP; i += 256) gB[i] = gbg[i];
  __syncthreads();

  float4 q = qarr[perm * 8 + qi];
  float nqx = -q.x, nqy = -q.y, nqz = -q.z, twoqw = 2.0f * q.w;
  float d[KNN];
#pragma unroll
  for (int i = 0; i < KNN; ++i) d[i] = INFINITY;

  auto dist = [&](float4 p) {
    return __builtin_fmaf(nqx, p.x, __builtin_fmaf(nqy, p.y,
           __builtin_fmaf(nqz, p.z, p.w)));
  };
  auto boxmd = [&](const float4* bx) {     // LDS box
    float4 lo = bx[0], hi = bx[1];
    float ax = fmaxf(fmaxf(lo.x - q.x, q.x - hi.x), 0.0f);
    float ay = fmaxf(fmaxf(lo.y - q.y, q.y - hi.y), 0.0f);
    float az = fmaxf(fmaxf(lo.z - q.z, q.z - hi.z), 0.0f);
    return __builtin_fmaf(ax, ax, __builtin_fmaf(ay, ay, az * az));
  };

  // Seed: rank-matched super (8 groups, independent unrolled loads).
  int ge = st[point_cell(q.x, q.y, q.z)];
  int geu = __shfl(ge, 4, 64);             // qi=4, slot=0 anchor
  int s0 = min(geu >> 7, 63);
#pragma unroll
  for (int k = 0; k < 8; ++k) {
    const float4* gp = parr + (s0 * 8 + k) * GSIZE;
    insert8(d, dist(gp[slot]));
    insert8(d, dist(gp[8 + slot]));
  }

  // Exact seed threshold: ONE full slot-merge; slot0 keeps it, others reset.
#pragma unroll
  for (int mm = 8; mm <= 32; mm <<= 1) {
    float od[KNN];
#pragma unroll
    for (int i = 0; i < KNN; ++i) od[i] = __shfl_xor(d[i], mm, 64);
#pragma unroll
    for (int i = 0; i < KNN; ++i) insert8(d, od[i]);
  }
  float thr = __builtin_fmaf(2.0f, d[KNN - 1], twoqw) * 1.00001f + 1e-5f;
  if (slot != 0) {
#pragma unroll
    for (int i = 0; i < KNN; ++i) d[i] = INFINITY;
  }

  // Flat tests: 512 group boxes in 64 unrolled rounds -> masks m[0..7]
  // (compile-time indices only; m[k] bit p <-> group k*64+p).
  unsigned long long m[8];
#pragma unroll
  for (int k = 0; k < 8; ++k) {
    unsigned long long acc = 0;
#pragma unroll
    for (int t2 = 0; t2 < 8; ++t2) {
      int g = (k * 8 + t2) * 8 + slot;
      unsigned long long bl = __ballot(boxmd(&gB[2 * g]) < thr);
      acc |= (unsigned long long)bytes_to_bits(bl) << (t2 * 8);
    }
    m[k] = acc;
  }
  // Exclude the seed super's 8 groups (byte s0&7 of mask s0>>3).
  {
    unsigned long long clr = ~(0xFFull << ((s0 & 7) * 8));
    switch (s0 >> 3) {
      case 0: m[0] &= clr; break; case 1: m[1] &= clr; break;
      case 2: m[2] &= clr; break; case 3: m[3] &= clr; break;
      case 4: m[4] &= clr; break; case 5: m[5] &= clr; break;
      case 6: m[6] &= clr; break; default: m[7] &= clr; break;
    }
  }

  // Drain: per-mask 2-deep pipeline (masks wave-uniform; loads coalesced).
#pragma unroll
  for (int k = 0; k < 8; ++k) {
    unsigned long long mk = m[k];
    int live0 = 0; float4 A0, B0;
    if (mk) {
      int p = (int)__builtin_ctzll(mk); mk &= mk - 1;
      const float4* gp = parr + (k * 64 + p) * GSIZE;
      live0 = 1; A0 = gp[slot]; B0 = gp[8 + slot];
    }
    while (live0) {
      int live1 = 0; float4 A1, B1;
      if (mk) {
        int p = (int)__builtin_ctzll(mk); mk &= mk - 1;
        const float4* gp = parr + (k * 64 + p) * GSIZE;
        live1 = 1; A1 = gp[slot]; B1 = gp[8 + slot];
      }
      insert8(d, dist(A0));
      insert8(d, dist(B0));
      live0 = live1; A0 = A1; B0 = B1;
    }
  }

  // Final merge of the 8 disjoint slot lists.
#pragma unroll
  for (int mm = 8; mm <= 32; mm <<= 1) {
    float od[KNN];
#pragma unroll
    for (int i = 0; i < KNN; ++i) od[i] = __shfl_xor(d[i], mm, 64);
#pragma unroll
    for (int i = 0; i < KNN; ++i) insert8(d, od[i]);
  }

  // Loss: slot 0 lanes (0..7) hold the 8 queries' merged lists.
  float val = 0.0f;
  if (slot == 0) {
    float s_ = 0.0f;
#pragma unroll
    for (int i = 0; i < KNN; ++i)
      s_ += sqrtf(fmaxf(__builtin_fmaf(2.0f, d[i], twoqw), 0.0f));
    val = s_ * (1.0f / KNN);
  }
  val += __shfl_down(val, 4, 64);
  val += __shfl_down(val, 2, 64);
  val += __shfl_down(val, 1, 64);
  if (lane == 0) bsum[wv] = val;
  __syncthreads();
  if (tid == 0)
    atomicAdd(out, (bsum[0] + bsum[1] + bsum[2] + bsum[3]) * (1.0f / (B * N)));
}

extern "C" void kernel_launch(void* const* d_in, const int* in_sizes, int n_in,
                              void* d_out, int out_size, void* d_ws, size_t ws_size,
                              hipStream_t stream) {
  const float* src = (const float*)d_in[0];
  const float* tgt = (const float*)d_in[1];
  const float* flow = (const float*)d_in[2];
  float* out = (float*)d_out;

  float4* pred_s = (float4*)d_ws;                        // 512 KB
  float4* tgt_s = pred_s + B * N;                        // 512 KB
  float4* gbox = tgt_s + B * N;                          // 128 KB
  int* starts = (int*)(gbox + NCB * 2 * NGRP);           // 131 KB

  prep_kernel<<<NCB, 1024, 0, stream>>>(src, tgt, flow, pred_s, tgt_s, starts,
                                        gbox, out);
  chamfer_kernel<<<(2 * B * N) / 32, 256, 0, stream>>>(pred_s, tgt_s, starts,
                                                       gbox, out);
}

// Round 11
// 144.564 us; speedup vs baseline: 1.3744x; 1.3744x over previous
//
#include <hip/hip_runtime.h>
#include <math.h>

constexpr int B = 4;
constexpr int N = 8192;
constexpr int KNN = 8;
constexpr int NCELL = 4096;              // 16^3 Morton cells
constexpr int GSIZE = 16;                // points per group
constexpr int NGRP = N / GSIZE;          // 512 groups per cloud-batch
constexpr int QPB = 64;                  // queries per block (chamfer)
constexpr int WAVES = 8;                 // waves per chamfer block
constexpr int NCB = 2 * B;               // cloud-batches (0-3 pred, 4-7 tgt)

// Insert tv into sorted ascending d[0..7]. Exact: d'[0]=min(d0,tv),
// d'[i]=med3(d[i-1],d[i],tv). 8 independent ops. INF insert is a no-op.
__device__ __forceinline__ void insert8(float (&d)[KNN], float tv) {
  float n0 = fminf(d[0], tv);
  float n1 = __builtin_amdgcn_fmed3f(d[0], d[1], tv);
  float n2 = __builtin_amdgcn_fmed3f(d[1], d[2], tv);
  float n3 = __builtin_amdgcn_fmed3f(d[2], d[3], tv);
  float n4 = __builtin_amdgcn_fmed3f(d[3], d[4], tv);
  float n5 = __builtin_amdgcn_fmed3f(d[4], d[5], tv);
  float n6 = __builtin_amdgcn_fmed3f(d[5], d[6], tv);
  float n7 = __builtin_amdgcn_fmed3f(d[6], d[7], tv);
  d[0] = n0; d[1] = n1; d[2] = n2; d[3] = n3;
  d[4] = n4; d[5] = n5; d[6] = n6; d[7] = n7;
}

__device__ __forceinline__ int morton3(int x, int y, int z) {
  int m = 0;
#pragma unroll
  for (int b = 0; b < 4; ++b)
    m |= (((x >> b) & 1) << (3 * b + 2)) | (((y >> b) & 1) << (3 * b + 1)) |
         (((z >> b) & 1) << (3 * b + 0));
  return m;
}

__device__ __forceinline__ int point_cell(float x, float y, float z) {
  int cx = (int)fminf(fmaxf((x + 4.0f) * 2.0f, 0.0f), 15.0f);
  int cy = (int)fminf(fmaxf((y + 4.0f) * 2.0f, 0.0f), 15.0f);
  int cz = (int)fminf(fmaxf((z + 4.0f) * 2.0f, 0.0f), 15.0f);
  return morton3(cx, cy, cz);
}

// One block per cloud-batch (8 blocks x 1024 threads). LDS histogram ->
// in-block scan (global starts) -> scatter (points in registers) ->
// group AABBs. Verified structure (absmax 0 since round 4).
__global__ __launch_bounds__(1024) void prep_kernel(
    const float* __restrict__ src, const float* __restrict__ tgt,
    const float* __restrict__ flow, float4* __restrict__ pred_s,
    float4* __restrict__ tgt_s, int* __restrict__ starts,
    float4* __restrict__ gbox, float* __restrict__ out) {
  __shared__ int hist[NCELL];              // 16 KB: counts -> cursor
  __shared__ int wsum[16];
  int tid = threadIdx.x, cb = blockIdx.x;
  int cloud = cb >> 2, batch = cb & 3;
  if (cb == 0 && tid == 0) out[0] = 0.0f;

  for (int i = tid; i < NCELL; i += 1024) hist[i] = 0;
  __syncthreads();

  const float* __restrict__ bp = (cloud == 0 ? src : tgt) + batch * N * 3;
  const float* __restrict__ bf = flow + batch * N * 3;
  float4 pt[8];
  int cell[8];
#pragma unroll
  for (int k = 0; k < 8; ++k) {
    int i = k * 1024 + tid;
    float x = bp[3 * i + 0], y = bp[3 * i + 1], z = bp[3 * i + 2];
    if (cloud == 0) { x += bf[3 * i + 0]; y += bf[3 * i + 1]; z += bf[3 * i + 2]; }
    pt[k] = make_float4(x, y, z, 0.5f * (x * x + y * y + z * z));
    cell[k] = point_cell(x, y, z);
    atomicAdd(&hist[cell[k]], 1);
  }
  __syncthreads();

  int b4 = tid * 4;
  int h0v = hist[b4 + 0], h1v = hist[b4 + 1];
  int h2v = hist[b4 + 2], h3v = hist[b4 + 3];
  int s = h0v + h1v + h2v + h3v;
  int lane = tid & 63, w = tid >> 6;
  int incl = s;
#pragma unroll
  for (int off = 1; off < 64; off <<= 1) {
    int u = __shfl_up(incl, off, 64);
    if (lane >= off) incl += u;
  }
  if (lane == 63) wsum[w] = incl;
  __syncthreads();
  if (tid < 16) {
    int v = wsum[tid], inc = v;
#pragma unroll
    for (int off = 1; off < 16; off <<= 1) {
      int u = __shfl_up(inc, off, 64);
      if (tid >= off) inc += u;
    }
    wsum[tid] = inc - v;
  }
  __syncthreads();
  int run = incl - s + wsum[w];
  int* __restrict__ stg = starts + cb * (NCELL + 1);
  stg[b4 + 0] = run; hist[b4 + 0] = run; run += h0v;
  stg[b4 + 1] = run; hist[b4 + 1] = run; run += h1v;
  stg[b4 + 2] = run; hist[b4 + 2] = run; run += h2v;
  stg[b4 + 3] = run; hist[b4 + 3] = run; run += h3v;
  if (tid == 0) stg[NCELL] = N;
  __syncthreads();

  float4* __restrict__ dst = (cloud == 0 ? pred_s : tgt_s) + batch * N;
#pragma unroll
  for (int k = 0; k < 8; ++k) {
    int pos = atomicAdd(&hist[cell[k]], 1);
    dst[pos] = pt[k];
  }
  __threadfence_block();
  __syncthreads();

  if (tid < NGRP) {
    const float4* __restrict__ sp = dst + tid * GSIZE;
    float lx = INFINITY, ly = INFINITY, lz = INFINITY;
    float hx = -INFINITY, hy = -INFINITY, hz = -INFINITY;
#pragma unroll
    for (int t = 0; t < GSIZE; ++t) {
      float4 p = sp[t];
      lx = fminf(lx, p.x); ly = fminf(ly, p.y); lz = fminf(lz, p.z);
      hx = fmaxf(hx, p.x); hy = fmaxf(hy, p.y); hz = fmaxf(hz, p.z);
    }
    gbox[cb * 2 * NGRP + 2 * tid + 0] = make_float4(lx, ly, lz, 0.0f);
    gbox[cb * 2 * NGRP + 2 * tid + 1] = make_float4(hx, hy, hz, 0.0f);
  }
}

// Round-2 chamfer, verbatim (measured 82.7 us, absmax 0): block = 8 waves x
// 64 lanes; lane = one sorted query. Wave w owns group residue class
// {g : g % 8 == w}. Best-first zigzag outward from the rank-matched group:
// test each box (LDS) against the CURRENT per-lane threshold, process only if
// any lane passes (dense: all 64 lanes, wave-uniform s_load candidate
// stream), tighten thr immediately. First group auto-passes (thr=INF) and
// self-seeds. Pruning exact: box-min lower-bounds dist^2, thr is monotone
// non-increasing, so a skip at any time is valid at the end (1e-5 margin
// covers fp rounding).
__global__ __launch_bounds__(512, 8) void chamfer_kernel(
    const float4* __restrict__ pred_s, const float4* __restrict__ tgt_s,
    const float4* __restrict__ aabb, float* __restrict__ out) {
  int blk = blockIdx.x;           // 1024 blocks
  int dir = blk >> 9;             // 0: pred->tgt, 1: tgt->pred
  int batch = (blk >> 7) & 3;
  int chunk = blk & 127;          // 128 chunks of 64 sorted queries
  const float4* __restrict__ qarr = (dir == 0 ? pred_s : tgt_s) + batch * N;
  const float4* __restrict__ parr = (dir == 0 ? tgt_s : pred_s) + batch * N;
  int ccb = (dir == 0 ? 4 + batch : batch);
  const float4* __restrict__ gb = aabb + ccb * (2 * NGRP);

  int lane = threadIdx.x & 63;
  int wv = __builtin_amdgcn_readfirstlane(threadIdx.x >> 6);

  __shared__ float4 boxes[2 * NGRP];            // 16 KB, shared by all waves
  __shared__ float part[WAVES][QPB][KNN + 1];   // 18 KB, slice merge

  for (int i = threadIdx.x; i < 2 * NGRP; i += 512) boxes[i] = gb[i];

  float4 q = qarr[chunk * QPB + lane];
  float nqx = -q.x, nqy = -q.y, nqz = -q.z;
  float two_qw = 2.0f * q.w;      // |q|^2

  float d[KNN];
#pragma unroll
  for (int i = 0; i < KNN; ++i) d[i] = INFINITY;
  float thr = INFINITY;

  __syncthreads();

  // Rank-matched start group index within this wave's residue class.
  int tc = (chunk * 4 + 6 - wv) >> 3;
  tc = max(0, min(63, tc));

  auto step = [&](int t) {
    int g = t * 8 + wv;                          // wave-uniform
    float4 lo = boxes[2 * g + 0];                // broadcast ds_read
    float4 hi = boxes[2 * g + 1];
    float dx = fmaxf(fmaxf(lo.x - q.x, q.x - hi.x), 0.0f);
    float dy = fmaxf(fmaxf(lo.y - q.y, q.y - hi.y), 0.0f);
    float dz = fmaxf(fmaxf(lo.z - q.z, q.z - hi.z), 0.0f);
    float md = __builtin_fmaf(dx, dx, __builtin_fmaf(dy, dy, dz * dz));
    if (__ballot(md < thr)) {
      const float4* __restrict__ gp = parr + g * GSIZE;  // uniform -> s_load
#pragma unroll
      for (int j = 0; j < GSIZE; ++j) {
        float4 p = gp[j];
        float tv = __builtin_fmaf(nqx, p.x, __builtin_fmaf(nqy, p.y,
                   __builtin_fmaf(nqz, p.z, p.w)));
        insert8(d, tv);
      }
      thr = __builtin_fmaf(2.0f, d[KNN - 1], two_qw) * 1.00001f + 1e-6f;
    }
  };

  for (int t = tc; t < 64; ++t) step(t);
  for (int t = tc - 1; t >= 0; --t) step(t);

  // Merge 8 waves' sorted top-8 per query through LDS (stride 9).
#pragma unroll
  for (int i = 0; i < KNN; ++i) part[wv][lane][i] = d[i];
  __syncthreads();

  if (wv == 0) {
    float m[KNN];
#pragma unroll
    for (int i = 0; i < KNN; ++i) m[i] = part[0][lane][i];
    for (int s = 1; s < WAVES; ++s) {
#pragma unroll
      for (int i = 0; i < KNN; ++i) insert8(m, part[s][lane][i]);
    }
    float s_ = 0.0f;
#pragma unroll
    for (int i = 0; i < KNN; ++i) {
      float d2 = fmaxf(__builtin_fmaf(2.0f, m[i], two_qw), 0.0f);
      s_ += sqrtf(d2);
    }
    float val = s_ * (1.0f / KNN);
    for (int off = 32; off; off >>= 1) val += __shfl_down(val, off, 64);
    if (lane == 0) atomicAdd(out, val * (1.0f / (B * N)));
  }
}

extern "C" void kernel_launch(void* const* d_in, const int* in_sizes, int n_in,
                              void* d_out, int out_size, void* d_ws, size_t ws_size,
                              hipStream_t stream) {
  const float* src = (const float*)d_in[0];
  const float* tgt = (const float*)d_in[1];
  const float* flow = (const float*)d_in[2];
  float* out = (float*)d_out;

  float4* pred_s = (float4*)d_ws;                        // 512 KB
  float4* tgt_s = pred_s + B * N;                        // 512 KB
  float4* gbox = tgt_s + B * N;                          // 128 KB
  int* starts = (int*)(gbox + NCB * 2 * NGRP);           // 131 KB

  prep_kernel<<<NCB, 1024, 0, stream>>>(src, tgt, flow, pred_s, tgt_s, starts,
                                        gbox, out);
  chamfer_kernel<<<2 * B * (N / QPB), 512, 0, stream>>>(pred_s, tgt_s, gbox, out);
}